// Round 4
// baseline (1272.314 us; speedup 1.0000x reference)
//
#include <hip/hip_runtime.h>

#define N_DB   100000
#define B_Q    1024
#define D_F    64
#define K_NN   100
#define JITTER 1e-6f
#define NS     12544   // prefix-sample cols = 98*128
#define STGT   40      // sample cum target (1/8 sample -> full count >= 100 w.h.p.)
#define CAP    4096    // per-row candidate capacity
#define TP     80      // padded LDS k-stride (bf16 elems)
#define AST    68      // k_regress LDS row stride (f32)

typedef __attribute__((ext_vector_type(8))) short bf16x8;
typedef __attribute__((ext_vector_type(4))) float f32x4;

__device__ __forceinline__ unsigned short f2b(float x) {   // f32 -> bf16 RNE
    unsigned u = __float_as_uint(x);
    u += 0x7FFF + ((u >> 16) & 1);
    return (unsigned short)(u >> 16);
}

// ---------------- squared norms ----------------
__global__ __launch_bounds__(256) void k_sqnorm(
    const float* __restrict__ db_X, const float* __restrict__ input,
    float* __restrict__ d2, float* __restrict__ x2) {
    int wave = (blockIdx.x * blockDim.x + threadIdx.x) >> 6;
    int lane = threadIdx.x & 63;
    if (wave >= N_DB + B_Q) return;
    const float* src = (wave < N_DB) ? (db_X + (size_t)wave * D_F)
                                     : (input + (size_t)(wave - N_DB) * D_F);
    float v = src[lane];
    float s = v * v;
    #pragma unroll
    for (int off = 32; off; off >>= 1) s += __shfl_xor(s, off, 64);
    if (lane == 0) {
        if (wave < N_DB) d2[wave] = s;
        else             x2[wave - N_DB] = s;
    }
}

// ---------------- shared GEMM staging (128x128 tile, 4 waves 2x2) ----------------
__device__ __forceinline__ void stage_tiles(
    const float* input, const float* db_X, const float* x2, const float* d2,
    unsigned short* As, unsigned short* Bs, float* x2s, float* d2s,
    int b0, int n0, int tid, bool guard) {
    #pragma unroll
    for (int it = 0; it < 8; it++) {                     // A: 2048 float4
        int f = it * 256 + tid;
        int r = f >> 4, k4 = f & 15;
        float4 w = *(const float4*)(input + (size_t)(b0 + r) * D_F + k4 * 4);
        uint2 p;
        p.x = (unsigned)f2b(w.x) | ((unsigned)f2b(w.y) << 16);
        p.y = (unsigned)f2b(w.z) | ((unsigned)f2b(w.w) << 16);
        *(uint2*)(&As[r * TP + k4 * 4]) = p;
    }
    #pragma unroll
    for (int it = 0; it < 8; it++) {                     // B: db rows
        int f = it * 256 + tid;
        int c = f >> 4, k4 = f & 15;
        int n = n0 + c;
        float4 w = make_float4(0.f, 0.f, 0.f, 0.f);
        if (!guard || n < N_DB) w = *(const float4*)(db_X + (size_t)n * D_F + k4 * 4);
        uint2 p;
        p.x = (unsigned)f2b(w.x) | ((unsigned)f2b(w.y) << 16);
        p.y = (unsigned)f2b(w.z) | ((unsigned)f2b(w.w) << 16);
        *(uint2*)(&Bs[c * TP + k4 * 4]) = p;
    }
    if (tid < 128) {
        x2s[tid] = x2[b0 + tid];
        int n = n0 + tid;
        d2s[tid] = (!guard || n < N_DB) ? d2[n] : 0.f;
    }
}

__device__ __forceinline__ void mfma_tile(
    const unsigned short* As, const unsigned short* Bs,
    int wr, int wc, int fr, int fq, f32x4 acc[4][4]) {
    #pragma unroll
    for (int ks = 0; ks < 2; ks++) {
        int koff = fq * 8 + ks * 32;
        bf16x8 a[4], b[4];
        #pragma unroll
        for (int i = 0; i < 4; i++)
            a[i] = *(const bf16x8*)(&As[(wr + i * 16 + fr) * TP + koff]);
        #pragma unroll
        for (int j = 0; j < 4; j++)
            b[j] = *(const bf16x8*)(&Bs[(wc + j * 16 + fr) * TP + koff]);
        #pragma unroll
        for (int i = 0; i < 4; i++)
            #pragma unroll
            for (int j = 0; j < 4; j++)
                acc[i][j] = __builtin_amdgcn_mfma_f32_16x16x32_bf16(a[i], b[j], acc[i][j], 0, 0, 0);
    }
}

// ---------------- sample GEMM -> byte bins (coalesced u32 stores) ----------------
__global__ __launch_bounds__(256) void k_gemm_sample(
    const float* __restrict__ input, const float* __restrict__ db_X,
    const float* __restrict__ x2, const float* __restrict__ d2,
    unsigned char* __restrict__ sbin) {
    __shared__ unsigned short As[128 * TP];
    __shared__ unsigned short Bs[128 * TP];
    __shared__ float x2s[128], d2s[128];
    int tid = threadIdx.x;
    int n0 = blockIdx.x * 128;
    int b0 = blockIdx.y * 128;
    stage_tiles(input, db_X, x2, d2, As, Bs, x2s, d2s, b0, n0, tid, false);
    __syncthreads();

    int lane = tid & 63, wid = tid >> 6;
    int wr = (wid >> 1) * 64, wc = (wid & 1) * 64;
    int fr = lane & 15, fq = lane >> 4;
    f32x4 acc[4][4];
    #pragma unroll
    for (int i = 0; i < 4; i++)
        #pragma unroll
        for (int j = 0; j < 4; j++) acc[i][j] = (f32x4){0.f, 0.f, 0.f, 0.f};
    mfma_tile(As, Bs, wr, wc, fr, fq, acc);

    const float inv_d = 1.0f / D_F;
    int jsel = fr >> 2;
    int base_src = (fq << 4) | (4 * (fr & 3));
    #pragma unroll
    for (int i = 0; i < 4; i++) {
        #pragma unroll
        for (int r = 0; r < 4; r++) {
            int row = wr + i * 16 + fq * 4 + r;
            float xx = x2s[row];
            unsigned p = 0;
            #pragma unroll
            for (int j = 0; j < 4; j++) {
                int col = wc + j * 16 + fr;
                float dv = (xx + d2s[col] - 2.0f * acc[i][j][r]) * inv_d;
                int bin = (int)(dv * 64.0f);
                bin = bin < 0 ? 0 : (bin > 255 ? 255 : bin);
                p |= (unsigned)bin << (8 * j);
            }
            unsigned out = 0;
            #pragma unroll
            for (int e = 0; e < 4; e++) {
                unsigned q = __shfl(p, base_src + e, 64);
                out |= ((q >> (8 * jsel)) & 255u) << (8 * e);
            }
            int ncol = n0 + wc + 4 * fr;
            *(unsigned*)(sbin + (size_t)(b0 + row) * NS + ncol) = out;
        }
    }
}

// ---------------- per-row sample histogram -> threshold bin ----------------
__global__ __launch_bounds__(256) void k_thr(
    const unsigned char* __restrict__ sbin, int* __restrict__ thr_t) {
    int b = blockIdx.x, tid = threadIdx.x;
    __shared__ int hist[256];
    hist[tid] = 0;
    __syncthreads();
    const uint4* row4 = (const uint4*)(sbin + (size_t)b * NS);
    for (int v = tid; v < NS / 16; v += 256) {
        uint4 w = row4[v];
        unsigned ws[4] = {w.x, w.y, w.z, w.w};
        #pragma unroll
        for (int q = 0; q < 4; q++)
            #pragma unroll
            for (int e = 0; e < 4; e++)
                atomicAdd(&hist[(ws[q] >> (8 * e)) & 255u], 1);
    }
    __syncthreads();
    if (tid == 0) {
        int cum = 0, t = 255;
        for (int i = 0; i < 256; i++) {
            cum += hist[i];
            if (cum >= STGT) { t = i; break; }
        }
        thr_t[b] = t;
    }
}

// ---------------- full GEMM -> direct candidate emission ----------------
__global__ __launch_bounds__(256) void k_gemm_cand(
    const float* __restrict__ input, const float* __restrict__ db_X,
    const float* __restrict__ x2, const float* __restrict__ d2,
    const int* __restrict__ thr_t, int* __restrict__ cnt,
    unsigned* __restrict__ cand) {
    __shared__ unsigned short As[128 * TP];
    __shared__ unsigned short Bs[128 * TP];
    __shared__ float x2s[128], d2s[128];
    __shared__ int thrL[128];
    int tid = threadIdx.x;
    int n0 = blockIdx.x * 128;
    int b0 = blockIdx.y * 128;
    stage_tiles(input, db_X, x2, d2, As, Bs, x2s, d2s, b0, n0, tid, true);
    if (tid < 128) {
        int t = thr_t[b0 + tid] + 2;
        thrL[tid] = t > 255 ? 255 : t;
    }
    __syncthreads();

    int lane = tid & 63, wid = tid >> 6;
    int wr = (wid >> 1) * 64, wc = (wid & 1) * 64;
    int fr = lane & 15, fq = lane >> 4;
    f32x4 acc[4][4];
    #pragma unroll
    for (int i = 0; i < 4; i++)
        #pragma unroll
        for (int j = 0; j < 4; j++) acc[i][j] = (f32x4){0.f, 0.f, 0.f, 0.f};
    mfma_tile(As, Bs, wr, wc, fr, fq, acc);

    const float inv_d = 1.0f / D_F;
    #pragma unroll
    for (int i = 0; i < 4; i++) {
        #pragma unroll
        for (int r = 0; r < 4; r++) {
            int row = wr + i * 16 + fq * 4 + r;
            int brow = b0 + row;
            float xx = x2s[row];
            int thrc = thrL[row];
            #pragma unroll
            for (int j = 0; j < 4; j++) {
                int n = n0 + wc + j * 16 + fr;
                float dv = (xx + d2s[wc + j * 16 + fr] - 2.0f * acc[i][j][r]) * inv_d;
                int bin = (int)(dv * 64.0f);
                bin = bin < 0 ? 0 : (bin > 255 ? 255 : bin);
                if (bin <= thrc && n < N_DB) {
                    int pos = atomicAdd(&cnt[brow], 1);
                    if (pos < CAP)
                        cand[(size_t)brow * CAP + pos] = (unsigned)n | ((unsigned)bin << 17);
                }
            }
        }
    }
}

// ---------------- per-row: verify, exact refine, rank (with exact fallback) ----------------
__global__ __launch_bounds__(256) void k_select(
    const int* __restrict__ cnt, const unsigned* __restrict__ cand,
    const int* __restrict__ thr_t, const float* __restrict__ input,
    const float* __restrict__ db_X, const float* __restrict__ x2,
    const float* __restrict__ d2, int* __restrict__ idx) {
    int b = blockIdx.x, tid = threadIdx.x, lane = tid & 63;
    __shared__ float xrow[64];
    __shared__ int hist[256];
    __shared__ int s_nle, s_cnt, s_t2;
    __shared__ int cand_n[CAP];
    __shared__ float cand_d[CAP];

    if (tid < 64) xrow[tid] = input[(size_t)b * 64 + tid];
    if (tid == 0) s_nle = 0;
    __syncthreads();

    int t = thr_t[b];
    int cr = cnt[b];
    int cn = cr > CAP ? CAP : cr;
    float xx = x2[b];

    int nle = 0;
    for (int c = tid; c < cn; c += 256) {
        unsigned p = cand[(size_t)b * CAP + c];
        cand_n[c] = (int)(p & 0x1FFFFu);
        nle += ((int)(p >> 17) <= t);
    }
    #pragma unroll
    for (int off = 32; off; off >>= 1) nle += __shfl_xor(nle, off, 64);
    if (lane == 0) atomicAdd(&s_nle, nle);
    __syncthreads();

    bool bad = (cr > CAP) || (s_nle < K_NN);
    int cnt_f;
    if (!bad) {
        cnt_f = cn;
        for (int c = tid; c < cnt_f; c += 256) {
            int n = cand_n[c];
            const float4* dr = (const float4*)(db_X + (size_t)n * D_F);
            float dot = 0.f;
            #pragma unroll
            for (int k = 0; k < 16; k++) {
                float4 w = dr[k];
                dot += xrow[k * 4 + 0] * w.x + xrow[k * 4 + 1] * w.y
                     + xrow[k * 4 + 2] * w.z + xrow[k * 4 + 3] * w.w;
            }
            cand_d[c] = (xx - 2.0f * dot + d2[n]) * (1.0f / D_F);
        }
    } else {
        // exact brute-force fallback (probability ~0, correctness guarantee)
        hist[tid] = 0;
        if (tid == 0) s_cnt = 0;
        __syncthreads();
        for (int n = tid; n < N_DB; n += 256) {
            const float4* dr = (const float4*)(db_X + (size_t)n * D_F);
            float dot = 0.f;
            #pragma unroll
            for (int k = 0; k < 16; k++) {
                float4 w = dr[k];
                dot += xrow[k * 4 + 0] * w.x + xrow[k * 4 + 1] * w.y
                     + xrow[k * 4 + 2] * w.z + xrow[k * 4 + 3] * w.w;
            }
            float d = (xx - 2.0f * dot + d2[n]) * (1.0f / D_F);
            int bn = (int)(d * 64.0f);
            bn = bn < 0 ? 0 : (bn > 255 ? 255 : bn);
            atomicAdd(&hist[bn], 1);
        }
        __syncthreads();
        if (tid == 0) {
            int cum = 0, t2 = 255;
            for (int i = 0; i < 256; i++) {
                cum += hist[i];
                if (cum >= K_NN) { t2 = i; break; }
            }
            s_t2 = t2;
        }
        __syncthreads();
        int t2 = s_t2;
        for (int n = tid; n < N_DB; n += 256) {
            const float4* dr = (const float4*)(db_X + (size_t)n * D_F);
            float dot = 0.f;
            #pragma unroll
            for (int k = 0; k < 16; k++) {
                float4 w = dr[k];
                dot += xrow[k * 4 + 0] * w.x + xrow[k * 4 + 1] * w.y
                     + xrow[k * 4 + 2] * w.z + xrow[k * 4 + 3] * w.w;
            }
            float d = (xx - 2.0f * dot + d2[n]) * (1.0f / D_F);
            int bn = (int)(d * 64.0f);
            bn = bn < 0 ? 0 : (bn > 255 ? 255 : bn);
            if (bn <= t2) {
                int pos = atomicAdd(&s_cnt, 1);
                if (pos < CAP) { cand_n[pos] = n; cand_d[pos] = d; }
            }
        }
        __syncthreads();
        cnt_f = s_cnt > CAP ? CAP : s_cnt;
    }
    __syncthreads();

    for (int c = tid; c < cnt_f; c += 256) {
        float dc = cand_d[c]; int nc = cand_n[c];
        int rank = 0;
        for (int j = 0; j < cnt_f; j++) {
            float dj = cand_d[j];
            rank += (dj < dc) || (dj == dc && cand_n[j] < nc);
        }
        if (rank < K_NN) idx[(size_t)b * K_NN + rank] = nc;
    }
}

// ---------------- per-row regression + loss (augmented RHS, wave back-sub) ----------------
__global__ __launch_bounds__(256) void k_regress(
    const float* __restrict__ input, const float* __restrict__ target,
    const float* __restrict__ db_X, const float* __restrict__ db_y,
    const int* __restrict__ idx, float* __restrict__ out) {
    int b = blockIdx.x, tid = threadIdx.x;
    __shared__ float A[K_NN * AST];          // [k][p], col0 = 1
    __shared__ float M[65 * AST];            // cols 0..64 AtA, col 65 = Aty
    __shared__ float v[65], xa[68], yv[K_NN];
    __shared__ int nbr[K_NN];

    if (tid < K_NN) {
        int n = idx[(size_t)b * K_NN + tid];
        nbr[tid] = n;
        yv[tid] = db_y[n];
    }
    if (tid < 64) xa[1 + tid] = input[(size_t)b * D_F + tid];
    if (tid == 0) { xa[0] = 1.f; xa[65] = xa[66] = xa[67] = 0.f; }
    __syncthreads();

    for (int f = tid; f < K_NN * AST; f += 256) {
        int k = f / AST, c = f - k * AST;
        float val = 0.f;
        if (c == 0) val = 1.f;
        else if (c <= 64) val = db_X[(size_t)nbr[k] * D_F + (c - 1)];
        A[f] = val;
    }
    __syncthreads();

    // AtA via 4x4 register tiles
    for (int tsk = tid; tsk < 289; tsk += 256) {
        int ti = tsk / 17, tj = tsk % 17;
        int p0 = ti * 4, q0 = tj * 4;
        float acc[4][4];
        #pragma unroll
        for (int ii = 0; ii < 4; ii++)
            #pragma unroll
            for (int jj = 0; jj < 4; jj++) acc[ii][jj] = 0.f;
        for (int k = 0; k < K_NN; k++) {
            float4 ap = *(const float4*)(&A[k * AST + p0]);
            float4 aq = *(const float4*)(&A[k * AST + q0]);
            float app[4] = {ap.x, ap.y, ap.z, ap.w};
            float aqq[4] = {aq.x, aq.y, aq.z, aq.w};
            #pragma unroll
            for (int ii = 0; ii < 4; ii++)
                #pragma unroll
                for (int jj = 0; jj < 4; jj++) acc[ii][jj] += app[ii] * aqq[jj];
        }
        #pragma unroll
        for (int ii = 0; ii < 4; ii++)
            #pragma unroll
            for (int jj = 0; jj < 4; jj++) {
                int p = p0 + ii, q = q0 + jj;
                if (p < 65 && q < 65)
                    M[p * AST + q] = acc[ii][jj] + (p == q ? JITTER : 0.f);
            }
    }
    for (int p = tid; p < 65; p += 256) {     // Aty -> augmented col 65
        float s = 0.f;
        for (int k = 0; k < K_NN; k++) s += A[k * AST + p] * yv[k];
        M[p * AST + 65] = s;
    }
    __syncthreads();

    // GE on cols j+1..65 (RHS rides along)
    for (int j = 0; j < 65; j++) {
        float inv = 1.0f / M[j * AST + j];
        for (int c = j + 1 + (tid & 63); c <= 65; c += 64) {
            float mjc = M[j * AST + c] * inv;
            for (int i = j + 1 + (tid >> 6); i <= 64; i += 4)
                M[i * AST + c] -= M[i * AST + j] * mjc;
        }
        __syncthreads();
    }

    // back-substitution: single wave, barrier-free
    if (tid < 64) {
        int i = tid;
        float ri = M[i * AST + 65];
        float di = M[i * AST + i];
        float x64 = M[64 * AST + 65] / M[64 * AST + 64];
        ri -= M[i * AST + 64] * x64;
        float xi_out = 0.f;
        for (int j = 63; j >= 0; j--) {
            float xj = __shfl(ri, j, 64) / __shfl(di, j, 64);
            if (i == j) xi_out = xj;
            if (i < j) ri -= M[i * AST + j] * xj;
        }
        v[i] = xi_out;
        if (i == 0) v[64] = x64;
    }
    __syncthreads();

    if (tid == 0) {
        float pred = 0.f;
        for (int q = 0; q <= 64; q++) pred += xa[q] * v[q];
        float e = pred - target[b];
        atomicAdd(out, e * e * (1.0f / B_Q));
    }
}

extern "C" void kernel_launch(void* const* d_in, const int* in_sizes, int n_in,
                              void* d_out, int out_size, void* d_ws, size_t ws_size,
                              hipStream_t stream) {
    const float* input  = (const float*)d_in[0];
    const float* target = (const float*)d_in[1];
    const float* db_X   = (const float*)d_in[2];
    const float* db_y   = (const float*)d_in[3];
    float* out = (float*)d_out;

    char* ws = (char*)d_ws;
    size_t off = 0;
    auto alloc = [&](size_t bytes) {
        size_t o = off;
        off += (bytes + 255) & ~(size_t)255;
        return o;
    };
    float*    d2    = (float*)(ws + alloc((size_t)N_DB * 4));
    float*    x2    = (float*)(ws + alloc((size_t)B_Q * 4));
    int*      idx   = (int*)(ws + alloc((size_t)B_Q * K_NN * 4));
    int*      thr_t = (int*)(ws + alloc((size_t)B_Q * 4));
    int*      cnt   = (int*)(ws + alloc((size_t)B_Q * 4));
    unsigned* cand  = (unsigned*)(ws + alloc((size_t)B_Q * CAP * 4));
    unsigned char* sbin = (unsigned char*)(ws + alloc((size_t)B_Q * NS));

    hipMemsetAsync(d_out, 0, sizeof(float) * out_size, stream);
    hipMemsetAsync(cnt, 0, (size_t)B_Q * 4, stream);

    {
        int waves = N_DB + B_Q;
        k_sqnorm<<<(waves + 3) / 4, 256, 0, stream>>>(db_X, input, d2, x2);
    }
    {
        dim3 g(NS / 128, B_Q / 128);
        k_gemm_sample<<<g, 256, 0, stream>>>(input, db_X, x2, d2, sbin);
    }
    k_thr<<<B_Q, 256, 0, stream>>>(sbin, thr_t);
    {
        dim3 g((N_DB + 127) / 128, B_Q / 128);
        k_gemm_cand<<<g, 256, 0, stream>>>(input, db_X, x2, d2, thr_t, cnt, cand);
    }
    k_select<<<B_Q, 256, 0, stream>>>(cnt, cand, thr_t, input, db_X, x2, d2, idx);
    k_regress<<<B_Q, 256, 0, stream>>>(input, target, db_X, db_y, idx, out);
}

// Round 5
// 913.903 us; speedup vs baseline: 1.3922x; 1.3922x over previous
//
#include <hip/hip_runtime.h>

#define N_DB   100000
#define B_Q    1024
#define D_F    64
#define K_NN   100
#define JITTER 1e-6f
#define NS     12544   // prefix-sample cols = 98*128
#define STGT   40      // sample cum target (1/8 sample -> full count >= 100 w.h.p.)
#define CAP    4096    // per-row global candidate capacity
#define BCAP   2048    // per-block LDS candidate staging capacity
#define TP     80      // padded LDS k-stride (bf16 elems)
#define AST    68      // k_regress LDS row stride (f32)

typedef __attribute__((ext_vector_type(8))) short bf16x8;
typedef __attribute__((ext_vector_type(4))) float f32x4;

__device__ __forceinline__ unsigned short f2b(float x) {   // f32 -> bf16 RNE
    unsigned u = __float_as_uint(x);
    u += 0x7FFF + ((u >> 16) & 1);
    return (unsigned short)(u >> 16);
}

// ---------------- squared norms ----------------
__global__ __launch_bounds__(256) void k_sqnorm(
    const float* __restrict__ db_X, const float* __restrict__ input,
    float* __restrict__ d2, float* __restrict__ x2) {
    int wave = (blockIdx.x * blockDim.x + threadIdx.x) >> 6;
    int lane = threadIdx.x & 63;
    if (wave >= N_DB + B_Q) return;
    const float* src = (wave < N_DB) ? (db_X + (size_t)wave * D_F)
                                     : (input + (size_t)(wave - N_DB) * D_F);
    float v = src[lane];
    float s = v * v;
    #pragma unroll
    for (int off = 32; off; off >>= 1) s += __shfl_xor(s, off, 64);
    if (lane == 0) {
        if (wave < N_DB) d2[wave] = s;
        else             x2[wave - N_DB] = s;
    }
}

// ---------------- shared GEMM staging (128x128 tile, 4 waves 2x2) ----------------
__device__ __forceinline__ void stage_tiles(
    const float* input, const float* db_X, const float* x2, const float* d2,
    unsigned short* As, unsigned short* Bs, float* x2s, float* d2s,
    int b0, int n0, int tid, bool guard) {
    #pragma unroll
    for (int it = 0; it < 8; it++) {                     // A: 2048 float4
        int f = it * 256 + tid;
        int r = f >> 4, k4 = f & 15;
        float4 w = *(const float4*)(input + (size_t)(b0 + r) * D_F + k4 * 4);
        uint2 p;
        p.x = (unsigned)f2b(w.x) | ((unsigned)f2b(w.y) << 16);
        p.y = (unsigned)f2b(w.z) | ((unsigned)f2b(w.w) << 16);
        *(uint2*)(&As[r * TP + k4 * 4]) = p;
    }
    #pragma unroll
    for (int it = 0; it < 8; it++) {                     // B: db rows
        int f = it * 256 + tid;
        int c = f >> 4, k4 = f & 15;
        int n = n0 + c;
        float4 w = make_float4(0.f, 0.f, 0.f, 0.f);
        if (!guard || n < N_DB) w = *(const float4*)(db_X + (size_t)n * D_F + k4 * 4);
        uint2 p;
        p.x = (unsigned)f2b(w.x) | ((unsigned)f2b(w.y) << 16);
        p.y = (unsigned)f2b(w.z) | ((unsigned)f2b(w.w) << 16);
        *(uint2*)(&Bs[c * TP + k4 * 4]) = p;
    }
    if (tid < 128) {
        x2s[tid] = x2[b0 + tid];
        int n = n0 + tid;
        d2s[tid] = (!guard || n < N_DB) ? d2[n] : 0.f;
    }
}

__device__ __forceinline__ void mfma_tile(
    const unsigned short* As, const unsigned short* Bs,
    int wr, int wc, int fr, int fq, f32x4 acc[4][4]) {
    #pragma unroll
    for (int ks = 0; ks < 2; ks++) {
        int koff = fq * 8 + ks * 32;
        bf16x8 a[4], b[4];
        #pragma unroll
        for (int i = 0; i < 4; i++)
            a[i] = *(const bf16x8*)(&As[(wr + i * 16 + fr) * TP + koff]);
        #pragma unroll
        for (int j = 0; j < 4; j++)
            b[j] = *(const bf16x8*)(&Bs[(wc + j * 16 + fr) * TP + koff]);
        #pragma unroll
        for (int i = 0; i < 4; i++)
            #pragma unroll
            for (int j = 0; j < 4; j++)
                acc[i][j] = __builtin_amdgcn_mfma_f32_16x16x32_bf16(a[i], b[j], acc[i][j], 0, 0, 0);
    }
}

// ---------------- sample GEMM -> byte bins (coalesced u32 stores) ----------------
__global__ __launch_bounds__(256) void k_gemm_sample(
    const float* __restrict__ input, const float* __restrict__ db_X,
    const float* __restrict__ x2, const float* __restrict__ d2,
    unsigned char* __restrict__ sbin) {
    __shared__ unsigned short As[128 * TP];
    __shared__ unsigned short Bs[128 * TP];
    __shared__ float x2s[128], d2s[128];
    int tid = threadIdx.x;
    int n0 = blockIdx.x * 128;
    int b0 = blockIdx.y * 128;
    stage_tiles(input, db_X, x2, d2, As, Bs, x2s, d2s, b0, n0, tid, false);
    __syncthreads();

    int lane = tid & 63, wid = tid >> 6;
    int wr = (wid >> 1) * 64, wc = (wid & 1) * 64;
    int fr = lane & 15, fq = lane >> 4;
    f32x4 acc[4][4];
    #pragma unroll
    for (int i = 0; i < 4; i++)
        #pragma unroll
        for (int j = 0; j < 4; j++) acc[i][j] = (f32x4){0.f, 0.f, 0.f, 0.f};
    mfma_tile(As, Bs, wr, wc, fr, fq, acc);

    const float inv_d = 1.0f / D_F;
    int jsel = fr >> 2;
    int base_src = (fq << 4) | (4 * (fr & 3));
    #pragma unroll
    for (int i = 0; i < 4; i++) {
        #pragma unroll
        for (int r = 0; r < 4; r++) {
            int row = wr + i * 16 + fq * 4 + r;
            float xx = x2s[row];
            unsigned p = 0;
            #pragma unroll
            for (int j = 0; j < 4; j++) {
                int col = wc + j * 16 + fr;
                float dv = (xx + d2s[col] - 2.0f * acc[i][j][r]) * inv_d;
                int bin = (int)(dv * 64.0f);
                bin = bin < 0 ? 0 : (bin > 255 ? 255 : bin);
                p |= (unsigned)bin << (8 * j);
            }
            unsigned out = 0;
            #pragma unroll
            for (int e = 0; e < 4; e++) {
                unsigned q = __shfl(p, base_src + e, 64);
                out |= ((q >> (8 * jsel)) & 255u) << (8 * e);
            }
            int ncol = n0 + wc + 4 * fr;
            *(unsigned*)(sbin + (size_t)(b0 + row) * NS + ncol) = out;
        }
    }
}

// ---------------- per-row sample histogram -> threshold bin ----------------
__global__ __launch_bounds__(256) void k_thr(
    const unsigned char* __restrict__ sbin, int* __restrict__ thr_t) {
    int b = blockIdx.x, tid = threadIdx.x;
    __shared__ int hist[256];
    hist[tid] = 0;
    __syncthreads();
    const uint4* row4 = (const uint4*)(sbin + (size_t)b * NS);
    for (int v = tid; v < NS / 16; v += 256) {
        uint4 w = row4[v];
        unsigned ws[4] = {w.x, w.y, w.z, w.w};
        #pragma unroll
        for (int q = 0; q < 4; q++)
            #pragma unroll
            for (int e = 0; e < 4; e++)
                atomicAdd(&hist[(ws[q] >> (8 * e)) & 255u], 1);
    }
    __syncthreads();
    if (tid == 0) {
        int cum = 0, t = 255;
        for (int i = 0; i < 256; i++) {
            cum += hist[i];
            if (cum >= STGT) { t = i; break; }
        }
        thr_t[b] = t;
    }
}

// ---------------- full GEMM -> candidates (B staged once, loop 8 query tiles) ----------------
__global__ __launch_bounds__(256) void k_gemm_cand(
    const float* __restrict__ input, const float* __restrict__ db_X,
    const float* __restrict__ x2, const float* __restrict__ d2,
    const int* __restrict__ thr_t, int* __restrict__ cnt,
    unsigned* __restrict__ cand) {
    __shared__ unsigned short As[128 * TP];
    __shared__ unsigned short Bs[128 * TP];
    __shared__ float x2s[128], d2s[128];
    __shared__ int thrL[128];
    __shared__ unsigned blist[BCAP];
    __shared__ int bcnt;
    int tid = threadIdx.x;
    int n0 = blockIdx.x * 128;

    // ---- stage B (db tile) once ----
    #pragma unroll
    for (int it = 0; it < 8; it++) {
        int f = it * 256 + tid;
        int c = f >> 4, k4 = f & 15;
        int n = n0 + c;
        float4 w = make_float4(0.f, 0.f, 0.f, 0.f);
        if (n < N_DB) w = *(const float4*)(db_X + (size_t)n * D_F + k4 * 4);
        uint2 p;
        p.x = (unsigned)f2b(w.x) | ((unsigned)f2b(w.y) << 16);
        p.y = (unsigned)f2b(w.z) | ((unsigned)f2b(w.w) << 16);
        *(uint2*)(&Bs[c * TP + k4 * 4]) = p;
    }
    if (tid < 128) {
        int n = n0 + tid;
        d2s[tid] = (n < N_DB) ? d2[n] : 0.f;
    }

    int lane = tid & 63, wid = tid >> 6;
    int wr = (wid >> 1) * 64, wc = (wid & 1) * 64;
    int fr = lane & 15, fq = lane >> 4;
    const float inv_d = 1.0f / D_F;

    for (int qs = 0; qs < 8; qs++) {
        int b0 = qs * 128;
        __syncthreads();                       // As free, prev blist flushed
        #pragma unroll
        for (int it = 0; it < 8; it++) {       // stage A sub-tile
            int f = it * 256 + tid;
            int r = f >> 4, k4 = f & 15;
            float4 w = *(const float4*)(input + (size_t)(b0 + r) * D_F + k4 * 4);
            uint2 p;
            p.x = (unsigned)f2b(w.x) | ((unsigned)f2b(w.y) << 16);
            p.y = (unsigned)f2b(w.z) | ((unsigned)f2b(w.w) << 16);
            *(uint2*)(&As[r * TP + k4 * 4]) = p;
        }
        if (tid < 128) {
            x2s[tid] = x2[b0 + tid];
            int t = thr_t[b0 + tid] + 2;       // +2: floor boundary + bf16 error
            thrL[tid] = t > 255 ? 255 : t;
        }
        if (tid == 0) bcnt = 0;
        __syncthreads();                       // As/x2s/thrL/bcnt ready

        f32x4 acc[4][4];
        #pragma unroll
        for (int i = 0; i < 4; i++)
            #pragma unroll
            for (int j = 0; j < 4; j++) acc[i][j] = (f32x4){0.f, 0.f, 0.f, 0.f};
        mfma_tile(As, Bs, wr, wc, fr, fq, acc);

        // epilogue: append hits to LDS list (overflow -> direct global, correctness-safe)
        #pragma unroll
        for (int i = 0; i < 4; i++) {
            #pragma unroll
            for (int r = 0; r < 4; r++) {
                int row = wr + i * 16 + fq * 4 + r;
                float xx = x2s[row];
                int thrc = thrL[row];
                #pragma unroll
                for (int j = 0; j < 4; j++) {
                    int col = wc + j * 16 + fr;
                    int n = n0 + col;
                    float dv = (xx + d2s[col] - 2.0f * acc[i][j][r]) * inv_d;
                    int bin = (int)(dv * 64.0f);
                    bin = bin < 0 ? 0 : (bin > 255 ? 255 : bin);
                    if (bin <= thrc && n < N_DB) {
                        unsigned packed = ((unsigned)row << 25) | ((unsigned)bin << 17) | (unsigned)n;
                        int pos = atomicAdd(&bcnt, 1);
                        if (pos < BCAP) blist[pos] = packed;
                        else {
                            int gp = atomicAdd(&cnt[b0 + row], 1);
                            if (gp < CAP)
                                cand[(size_t)(b0 + row) * CAP + gp] = packed & 0x1FFFFFFu;
                        }
                    }
                }
            }
        }
        __syncthreads();                       // blist complete

        int total = bcnt > BCAP ? BCAP : bcnt; // parallel flush: 1 atomic+store per entry
        for (int e = tid; e < total; e += 256) {
            unsigned p = blist[e];
            int brow = b0 + (int)(p >> 25);
            int pos = atomicAdd(&cnt[brow], 1);
            if (pos < CAP) cand[(size_t)brow * CAP + pos] = p & 0x1FFFFFFu;
        }
    }
}

// ---------------- per-row: verify, exact refine, rank (with exact fallback) ----------------
__global__ __launch_bounds__(256) void k_select(
    const int* __restrict__ cnt, const unsigned* __restrict__ cand,
    const int* __restrict__ thr_t, const float* __restrict__ input,
    const float* __restrict__ db_X, const float* __restrict__ x2,
    const float* __restrict__ d2, int* __restrict__ idx) {
    int b = blockIdx.x, tid = threadIdx.x, lane = tid & 63;
    __shared__ float xrow[64];
    __shared__ int hist[256];
    __shared__ int s_nle, s_cnt, s_t2;
    __shared__ int cand_n[CAP];
    __shared__ float cand_d[CAP];

    if (tid < 64) xrow[tid] = input[(size_t)b * 64 + tid];
    if (tid == 0) s_nle = 0;
    __syncthreads();

    int t = thr_t[b];
    int cr = cnt[b];
    int cn = cr > CAP ? CAP : cr;
    float xx = x2[b];

    int nle = 0;
    for (int c = tid; c < cn; c += 256) {
        unsigned p = cand[(size_t)b * CAP + c];
        cand_n[c] = (int)(p & 0x1FFFFu);
        nle += ((int)(p >> 17) <= t);
    }
    #pragma unroll
    for (int off = 32; off; off >>= 1) nle += __shfl_xor(nle, off, 64);
    if (lane == 0) atomicAdd(&s_nle, nle);
    __syncthreads();

    bool bad = (cr > CAP) || (s_nle < K_NN);
    int cnt_f;
    if (!bad) {
        cnt_f = cn;
        for (int c = tid; c < cnt_f; c += 256) {
            int n = cand_n[c];
            const float4* dr = (const float4*)(db_X + (size_t)n * D_F);
            float dot = 0.f;
            #pragma unroll
            for (int k = 0; k < 16; k++) {
                float4 w = dr[k];
                dot += xrow[k * 4 + 0] * w.x + xrow[k * 4 + 1] * w.y
                     + xrow[k * 4 + 2] * w.z + xrow[k * 4 + 3] * w.w;
            }
            cand_d[c] = (xx - 2.0f * dot + d2[n]) * (1.0f / D_F);
        }
    } else {
        // exact brute-force fallback (probability ~0, correctness guarantee)
        hist[tid] = 0;
        if (tid == 0) s_cnt = 0;
        __syncthreads();
        for (int n = tid; n < N_DB; n += 256) {
            const float4* dr = (const float4*)(db_X + (size_t)n * D_F);
            float dot = 0.f;
            #pragma unroll
            for (int k = 0; k < 16; k++) {
                float4 w = dr[k];
                dot += xrow[k * 4 + 0] * w.x + xrow[k * 4 + 1] * w.y
                     + xrow[k * 4 + 2] * w.z + xrow[k * 4 + 3] * w.w;
            }
            float d = (xx - 2.0f * dot + d2[n]) * (1.0f / D_F);
            int bn = (int)(d * 64.0f);
            bn = bn < 0 ? 0 : (bn > 255 ? 255 : bn);
            atomicAdd(&hist[bn], 1);
        }
        __syncthreads();
        if (tid == 0) {
            int cum = 0, t2 = 255;
            for (int i = 0; i < 256; i++) {
                cum += hist[i];
                if (cum >= K_NN) { t2 = i; break; }
            }
            s_t2 = t2;
        }
        __syncthreads();
        int t2 = s_t2;
        for (int n = tid; n < N_DB; n += 256) {
            const float4* dr = (const float4*)(db_X + (size_t)n * D_F);
            float dot = 0.f;
            #pragma unroll
            for (int k = 0; k < 16; k++) {
                float4 w = dr[k];
                dot += xrow[k * 4 + 0] * w.x + xrow[k * 4 + 1] * w.y
                     + xrow[k * 4 + 2] * w.z + xrow[k * 4 + 3] * w.w;
            }
            float d = (xx - 2.0f * dot + d2[n]) * (1.0f / D_F);
            int bn = (int)(d * 64.0f);
            bn = bn < 0 ? 0 : (bn > 255 ? 255 : bn);
            if (bn <= t2) {
                int pos = atomicAdd(&s_cnt, 1);
                if (pos < CAP) { cand_n[pos] = n; cand_d[pos] = d; }
            }
        }
        __syncthreads();
        cnt_f = s_cnt > CAP ? CAP : s_cnt;
    }
    __syncthreads();

    for (int c = tid; c < cnt_f; c += 256) {
        float dc = cand_d[c]; int nc = cand_n[c];
        int rank = 0;
        for (int j = 0; j < cnt_f; j++) {
            float dj = cand_d[j];
            rank += (dj < dc) || (dj == dc && cand_n[j] < nc);
        }
        if (rank < K_NN) idx[(size_t)b * K_NN + rank] = nc;
    }
}

// ---------------- per-row regression + loss (augmented RHS, wave back-sub) ----------------
__global__ __launch_bounds__(256) void k_regress(
    const float* __restrict__ input, const float* __restrict__ target,
    const float* __restrict__ db_X, const float* __restrict__ db_y,
    const int* __restrict__ idx, float* __restrict__ out) {
    int b = blockIdx.x, tid = threadIdx.x;
    __shared__ float A[K_NN * AST];          // [k][p], col0 = 1
    __shared__ float M[65 * AST];            // cols 0..64 AtA, col 65 = Aty
    __shared__ float v[65], xa[68], yv[K_NN];
    __shared__ int nbr[K_NN];

    if (tid < K_NN) {
        int n = idx[(size_t)b * K_NN + tid];
        nbr[tid] = n;
        yv[tid] = db_y[n];
    }
    if (tid < 64) xa[1 + tid] = input[(size_t)b * D_F + tid];
    if (tid == 0) { xa[0] = 1.f; xa[65] = xa[66] = xa[67] = 0.f; }
    __syncthreads();

    for (int f = tid; f < K_NN * AST; f += 256) {
        int k = f / AST, c = f - k * AST;
        float val = 0.f;
        if (c == 0) val = 1.f;
        else if (c <= 64) val = db_X[(size_t)nbr[k] * D_F + (c - 1)];
        A[f] = val;
    }
    __syncthreads();

    // AtA via 4x4 register tiles
    for (int tsk = tid; tsk < 289; tsk += 256) {
        int ti = tsk / 17, tj = tsk % 17;
        int p0 = ti * 4, q0 = tj * 4;
        float acc[4][4];
        #pragma unroll
        for (int ii = 0; ii < 4; ii++)
            #pragma unroll
            for (int jj = 0; jj < 4; jj++) acc[ii][jj] = 0.f;
        for (int k = 0; k < K_NN; k++) {
            float4 ap = *(const float4*)(&A[k * AST + p0]);
            float4 aq = *(const float4*)(&A[k * AST + q0]);
            float app[4] = {ap.x, ap.y, ap.z, ap.w};
            float aqq[4] = {aq.x, aq.y, aq.z, aq.w};
            #pragma unroll
            for (int ii = 0; ii < 4; ii++)
                #pragma unroll
                for (int jj = 0; jj < 4; jj++) acc[ii][jj] += app[ii] * aqq[jj];
        }
        #pragma unroll
        for (int ii = 0; ii < 4; ii++)
            #pragma unroll
            for (int jj = 0; jj < 4; jj++) {
                int p = p0 + ii, q = q0 + jj;
                if (p < 65 && q < 65)
                    M[p * AST + q] = acc[ii][jj] + (p == q ? JITTER : 0.f);
            }
    }
    for (int p = tid; p < 65; p += 256) {     // Aty -> augmented col 65
        float s = 0.f;
        for (int k = 0; k < K_NN; k++) s += A[k * AST + p] * yv[k];
        M[p * AST + 65] = s;
    }
    __syncthreads();

    // GE on cols j+1..65 (RHS rides along)
    for (int j = 0; j < 65; j++) {
        float inv = 1.0f / M[j * AST + j];
        for (int c = j + 1 + (tid & 63); c <= 65; c += 64) {
            float mjc = M[j * AST + c] * inv;
            for (int i = j + 1 + (tid >> 6); i <= 64; i += 4)
                M[i * AST + c] -= M[i * AST + j] * mjc;
        }
        __syncthreads();
    }

    // back-substitution: single wave, barrier-free
    if (tid < 64) {
        int i = tid;
        float ri = M[i * AST + 65];
        float di = M[i * AST + i];
        float x64 = M[64 * AST + 65] / M[64 * AST + 64];
        ri -= M[i * AST + 64] * x64;
        float xi_out = 0.f;
        for (int j = 63; j >= 0; j--) {
            float xj = __shfl(ri, j, 64) / __shfl(di, j, 64);
            if (i == j) xi_out = xj;
            if (i < j) ri -= M[i * AST + j] * xj;
        }
        v[i] = xi_out;
        if (i == 0) v[64] = x64;
    }
    __syncthreads();

    if (tid == 0) {
        float pred = 0.f;
        for (int q = 0; q <= 64; q++) pred += xa[q] * v[q];
        float e = pred - target[b];
        atomicAdd(out, e * e * (1.0f / B_Q));
    }
}

extern "C" void kernel_launch(void* const* d_in, const int* in_sizes, int n_in,
                              void* d_out, int out_size, void* d_ws, size_t ws_size,
                              hipStream_t stream) {
    const float* input  = (const float*)d_in[0];
    const float* target = (const float*)d_in[1];
    const float* db_X   = (const float*)d_in[2];
    const float* db_y   = (const float*)d_in[3];
    float* out = (float*)d_out;

    char* ws = (char*)d_ws;
    size_t off = 0;
    auto alloc = [&](size_t bytes) {
        size_t o = off;
        off += (bytes + 255) & ~(size_t)255;
        return o;
    };
    float*    d2    = (float*)(ws + alloc((size_t)N_DB * 4));
    float*    x2    = (float*)(ws + alloc((size_t)B_Q * 4));
    int*      idx   = (int*)(ws + alloc((size_t)B_Q * K_NN * 4));
    int*      thr_t = (int*)(ws + alloc((size_t)B_Q * 4));
    int*      cnt   = (int*)(ws + alloc((size_t)B_Q * 4));
    unsigned* cand  = (unsigned*)(ws + alloc((size_t)B_Q * CAP * 4));
    unsigned char* sbin = (unsigned char*)(ws + alloc((size_t)B_Q * NS));

    hipMemsetAsync(d_out, 0, sizeof(float) * out_size, stream);
    hipMemsetAsync(cnt, 0, (size_t)B_Q * 4, stream);

    {
        int waves = N_DB + B_Q;
        k_sqnorm<<<(waves + 3) / 4, 256, 0, stream>>>(db_X, input, d2, x2);
    }
    {
        dim3 g(NS / 128, B_Q / 128);
        k_gemm_sample<<<g, 256, 0, stream>>>(input, db_X, x2, d2, sbin);
    }
    k_thr<<<B_Q, 256, 0, stream>>>(sbin, thr_t);
    k_gemm_cand<<<(N_DB + 127) / 128, 256, 0, stream>>>(input, db_X, x2, d2, thr_t, cnt, cand);
    k_select<<<B_Q, 256, 0, stream>>>(cnt, cand, thr_t, input, db_X, x2, d2, idx);
    k_regress<<<B_Q, 256, 0, stream>>>(input, target, db_X, db_y, idx, out);
}

// Round 8
// 585.993 us; speedup vs baseline: 2.1712x; 1.5596x over previous
//
#include <hip/hip_runtime.h>

#define N_DB   100000
#define B_Q    1024
#define D_F    64
#define K_NN   100
#define JITTER 1e-6f
#define NS     12544   // prefix-sample cols = 98*128
#define STGT   40      // sample cum target (1/8 sample -> full count >= 100 w.h.p.)
#define CAP    3072    // per-row candidate capacity
#define BCAP   2048    // per-block LDS staging capacity
#define BB     512     // boundary-bin capacity in k_rank
#define TP     80      // padded LDS k-stride (bf16 elems)
#define AST    68      // k_regress LDS row stride (f32)

typedef __attribute__((ext_vector_type(8))) short bf16x8;
typedef __attribute__((ext_vector_type(4))) float f32x4;

__device__ __forceinline__ unsigned short f2b(float x) {   // f32 -> bf16 RNE
    unsigned u = __float_as_uint(x);
    u += 0x7FFF + ((u >> 16) & 1);
    return (unsigned short)(u >> 16);
}

// ---------------- bf16 copies of db_X and input ----------------
__global__ __launch_bounds__(256) void k_prep(
    const float* __restrict__ db_X, const float* __restrict__ input,
    unsigned short* __restrict__ dbb, unsigned short* __restrict__ inb) {
    const int total4 = (N_DB + B_Q) * 16;
    for (int v = blockIdx.x * 256 + threadIdx.x; v < total4; v += gridDim.x * 256) {
        const float* src; unsigned short* dst;
        if (v < N_DB * 16) { src = db_X + (size_t)v * 4; dst = dbb + (size_t)v * 4; }
        else { int u = v - N_DB * 16; src = input + (size_t)u * 4; dst = inb + (size_t)u * 4; }
        float4 w = *(const float4*)src;
        ushort4 o = { f2b(w.x), f2b(w.y), f2b(w.z), f2b(w.w) };
        *(ushort4*)dst = o;
    }
}

// ---------------- squared norms ----------------
__global__ __launch_bounds__(256) void k_sqnorm(
    const float* __restrict__ db_X, const float* __restrict__ input,
    float* __restrict__ d2, float* __restrict__ x2) {
    int wave = (blockIdx.x * blockDim.x + threadIdx.x) >> 6;
    int lane = threadIdx.x & 63;
    if (wave >= N_DB + B_Q) return;
    const float* src = (wave < N_DB) ? (db_X + (size_t)wave * D_F)
                                     : (input + (size_t)(wave - N_DB) * D_F);
    float v = src[lane];
    float s = v * v;
    #pragma unroll
    for (int off = 32; off; off >>= 1) s += __shfl_xor(s, off, 64);
    if (lane == 0) {
        if (wave < N_DB) d2[wave] = s;
        else             x2[wave - N_DB] = s;
    }
}

// ---------------- bf16 tile staging (from preconverted arrays) ----------------
__device__ __forceinline__ void stage_rows_bf16(
    const unsigned short* __restrict__ src, unsigned short* dst,
    int n0, int tid, bool guard) {
    #pragma unroll
    for (int it = 0; it < 4; it++) {               // 1024 short8 = 128 rows x 8 chunks
        int f = it * 256 + tid;
        int c = f >> 3, k8 = f & 7;
        int n = n0 + c;
        uint4 w = make_uint4(0u, 0u, 0u, 0u);
        if (!guard || n < N_DB) w = *(const uint4*)(src + (size_t)n * 64 + k8 * 8);
        *(uint4*)(&dst[c * TP + k8 * 8]) = w;
    }
}

__device__ __forceinline__ void mfma_tile(
    const unsigned short* As, const unsigned short* Bs,
    int wr, int wc, int fr, int fq, f32x4 acc[4][4]) {
    #pragma unroll
    for (int ks = 0; ks < 2; ks++) {
        int koff = fq * 8 + ks * 32;
        bf16x8 a[4], b[4];
        #pragma unroll
        for (int i = 0; i < 4; i++)
            a[i] = *(const bf16x8*)(&As[(wr + i * 16 + fr) * TP + koff]);
        #pragma unroll
        for (int j = 0; j < 4; j++)
            b[j] = *(const bf16x8*)(&Bs[(wc + j * 16 + fr) * TP + koff]);
        #pragma unroll
        for (int i = 0; i < 4; i++)
            #pragma unroll
            for (int j = 0; j < 4; j++)
                acc[i][j] = __builtin_amdgcn_mfma_f32_16x16x32_bf16(a[i], b[j], acc[i][j], 0, 0, 0);
    }
}

// ---------------- sample GEMM -> byte bins (B resident, loop 8 query tiles) ----------------
__global__ __launch_bounds__(256) void k_gemm_sample(
    const unsigned short* __restrict__ inb, const unsigned short* __restrict__ dbb,
    const float* __restrict__ x2, const float* __restrict__ d2,
    unsigned char* __restrict__ sbin) {
    __shared__ unsigned short As[128 * TP];
    __shared__ unsigned short Bs[128 * TP];
    __shared__ float x2s[128], d2s[128];
    int tid = threadIdx.x;
    int n0 = blockIdx.x * 128;                     // n0+127 < NS <= N_DB

    stage_rows_bf16(dbb, Bs, n0, tid, false);
    if (tid < 128) d2s[tid] = d2[n0 + tid];

    int lane = tid & 63, wid = tid >> 6;
    int wr = (wid >> 1) * 64, wc = (wid & 1) * 64;
    int fr = lane & 15, fq = lane >> 4;
    const float inv_d = 1.0f / D_F;
    int jsel = fr >> 2;
    int base_src = (fq << 4) | (4 * (fr & 3));

    for (int qs = 0; qs < 8; qs++) {
        int b0 = qs * 128;
        __syncthreads();                           // prev epilogue done with As/x2s
        stage_rows_bf16(inb, As, b0, tid, false);
        if (tid < 128) x2s[tid] = x2[b0 + tid];
        __syncthreads();

        f32x4 acc[4][4];
        #pragma unroll
        for (int i = 0; i < 4; i++)
            #pragma unroll
            for (int j = 0; j < 4; j++) acc[i][j] = (f32x4){0.f, 0.f, 0.f, 0.f};
        mfma_tile(As, Bs, wr, wc, fr, fq, acc);

        #pragma unroll
        for (int i = 0; i < 4; i++) {
            #pragma unroll
            for (int r = 0; r < 4; r++) {
                int row = wr + i * 16 + fq * 4 + r;    // C/D: col=lane&15, row=(lane>>4)*4+reg
                float xx = x2s[row];
                unsigned p = 0;
                #pragma unroll
                for (int j = 0; j < 4; j++) {
                    int col = wc + j * 16 + fr;
                    float dv = (xx + d2s[col] - 2.0f * acc[i][j][r]) * inv_d;
                    int bin = (int)(dv * 64.0f);
                    bin = bin < 0 ? 0 : (bin > 255 ? 255 : bin);
                    p |= (unsigned)bin << (8 * j);
                }
                unsigned out = 0;
                #pragma unroll
                for (int e = 0; e < 4; e++) {
                    unsigned q = __shfl(p, base_src + e, 64);
                    out |= ((q >> (8 * jsel)) & 255u) << (8 * e);
                }
                int ncol = n0 + wc + 4 * fr;
                *(unsigned*)(sbin + (size_t)(b0 + row) * NS + ncol) = out;
            }
        }
    }
}

// ---------------- per-row sample histogram -> threshold bin ----------------
__global__ __launch_bounds__(256) void k_thr(
    const unsigned char* __restrict__ sbin, int* __restrict__ thr_t) {
    int b = blockIdx.x, tid = threadIdx.x;
    __shared__ int hist[256];
    hist[tid] = 0;
    __syncthreads();
    const uint4* row4 = (const uint4*)(sbin + (size_t)b * NS);
    for (int v = tid; v < NS / 16; v += 256) {
        uint4 w = row4[v];
        unsigned ws[4] = {w.x, w.y, w.z, w.w};
        #pragma unroll
        for (int q = 0; q < 4; q++)
            #pragma unroll
            for (int e = 0; e < 4; e++)
                atomicAdd(&hist[(ws[q] >> (8 * e)) & 255u], 1);
    }
    __syncthreads();
    if (tid == 0) {
        int cum = 0, t = 255;
        for (int i = 0; i < 256; i++) {
            cum += hist[i];
            if (cum >= STGT) { t = i; break; }
        }
        thr_t[b] = t;
    }
}

// ---------------- full GEMM -> candidate indices + tight counts ----------------
// loose emit: 64*dv < t+3  <=>  acc > (xx-(t+3))/2 + d2/2
// tight cnt:  64*dv < t+1  <=>  acc > (xx-(t+1))/2 + d2/2   (== old "bin<=t" verify)
__global__ __launch_bounds__(256) void k_gemm_cand(
    const unsigned short* __restrict__ inb, const unsigned short* __restrict__ dbb,
    const float* __restrict__ x2, const float* __restrict__ d2,
    const int* __restrict__ thr_t, int* __restrict__ cnt,
    int* __restrict__ nle, unsigned* __restrict__ cand) {
    __shared__ unsigned short As[128 * TP];
    __shared__ unsigned short Bs[128 * TP];
    __shared__ float d2h[128], rl[128], rt[128];
    __shared__ int rcnt[128];
    __shared__ unsigned blist[BCAP];
    __shared__ int bcnt;
    int tid = threadIdx.x;
    int n0 = blockIdx.x * 128;

    stage_rows_bf16(dbb, Bs, n0, tid, true);
    if (tid < 128) {
        int n = n0 + tid;
        d2h[tid] = (n < N_DB) ? d2[n] * 0.5f : 1e30f;  // pad cols can never hit
    }

    int lane = tid & 63, wid = tid >> 6;
    int wr = (wid >> 1) * 64, wc = (wid & 1) * 64;
    int fr = lane & 15, fq = lane >> 4;

    for (int qs = 0; qs < 8; qs++) {
        int b0 = qs * 128;
        __syncthreads();                           // prev flush complete; As free
        stage_rows_bf16(inb, As, b0, tid, false);
        if (tid < 128) {
            float xx = x2[b0 + tid];
            int t = thr_t[b0 + tid];
            rl[tid] = (xx - (float)(t + 3)) * 0.5f;
            rt[tid] = (xx - (float)(t + 1)) * 0.5f;
            rcnt[tid] = 0;
        }
        if (tid == 0) bcnt = 0;
        __syncthreads();

        f32x4 acc[4][4];
        #pragma unroll
        for (int i = 0; i < 4; i++)
            #pragma unroll
            for (int j = 0; j < 4; j++) acc[i][j] = (f32x4){0.f, 0.f, 0.f, 0.f};
        mfma_tile(As, Bs, wr, wc, fr, fq, acc);

        #pragma unroll
        for (int i = 0; i < 4; i++) {
            #pragma unroll
            for (int r = 0; r < 4; r++) {
                int row = wr + i * 16 + fq * 4 + r;
                float rlv = rl[row], rtv = rt[row];
                #pragma unroll
                for (int j = 0; j < 4; j++) {
                    int col = wc + j * 16 + fr;
                    float a = acc[i][j][r];
                    float dh = d2h[col];
                    if (a > rlv + dh) {            // loose hit (superset)
                        unsigned packed = ((unsigned)row << 17) | (unsigned)(n0 + col);
                        int pos = atomicAdd(&bcnt, 1);
                        if (pos < BCAP) blist[pos] = packed;
                        else {
                            int gp = atomicAdd(&cnt[b0 + row], 1);
                            if (gp < CAP) cand[(size_t)(b0 + row) * CAP + gp] = packed & 0x1FFFFu;
                        }
                        if (a > rtv + dh) atomicAdd(&rcnt[row], 1);   // tight
                    }
                }
            }
        }
        __syncthreads();                           // blist/rcnt complete

        int total = bcnt > BCAP ? BCAP : bcnt;
        for (int e = tid; e < total; e += 256) {
            unsigned p = blist[e];
            int brow = b0 + (int)(p >> 17);
            int pos = atomicAdd(&cnt[brow], 1);
            if (pos < CAP) cand[(size_t)brow * CAP + pos] = p & 0x1FFFFu;
        }
        if (tid < 128 && rcnt[tid] > 0) atomicAdd(&nle[b0 + tid], rcnt[tid]);
    }
}

// ---------------- exact f32 distance for each candidate ----------------
__global__ __launch_bounds__(256) void k_refine(
    const int* __restrict__ cnt, const unsigned* __restrict__ cand,
    const float* __restrict__ input, const float* __restrict__ db_X,
    const float* __restrict__ x2, const float* __restrict__ d2,
    float* __restrict__ cd) {
    int b = blockIdx.x, tid = threadIdx.x;
    __shared__ float xrow[64];
    if (tid < 64) xrow[tid] = input[(size_t)b * 64 + tid];
    __syncthreads();
    int cn = cnt[b]; if (cn > CAP) cn = CAP;
    float xx = x2[b];
    for (int c = tid; c < cn; c += 256) {
        int n = (int)(cand[(size_t)b * CAP + c] & 0x1FFFFu);
        const float4* dr = (const float4*)(db_X + (size_t)n * D_F);
        float dot = 0.f;
        #pragma unroll
        for (int k = 0; k < 16; k++) {
            float4 w = dr[k];
            dot += xrow[k * 4 + 0] * w.x + xrow[k * 4 + 1] * w.y
                 + xrow[k * 4 + 2] * w.z + xrow[k * 4 + 3] * w.w;
        }
        cd[(size_t)b * CAP + c] = (xx - 2.0f * dot + d2[n]) * (1.0f / D_F);
    }
}

// ---------------- exact top-100 via fine histogram + boundary mini-rank ----------------
__global__ __launch_bounds__(256) void k_rank(
    const int* __restrict__ cnt, const int* __restrict__ nle,
    const unsigned* __restrict__ cand, const float* __restrict__ cd,
    const int* __restrict__ thr_t, const float* __restrict__ input,
    const float* __restrict__ db_X, const float* __restrict__ x2,
    const float* __restrict__ d2, int* __restrict__ idx) {
    int b = blockIdx.x, tid = threadIdx.x;
    __shared__ float ldist[CAP];
    __shared__ int lidx[CAP];
    __shared__ int hist[1024];
    __shared__ int s4[256];
    __shared__ float bbd[BB];
    __shared__ int bbn[BB];
    __shared__ int s_b100, s_c0, s_out, s_bb;
    __shared__ float xrow[64];

    if (tid < 64) xrow[tid] = input[(size_t)b * 64 + tid];
    #pragma unroll
    for (int h = 0; h < 4; h++) hist[h * 256 + tid] = 0;
    if (tid == 0) { s_out = 0; s_bb = 0; }
    __syncthreads();

    int cr = cnt[b];
    int cn = cr > CAP ? CAP : cr;
    bool bad = (cr > CAP) || (nle[b] < K_NN);
    float xx = x2[b];

    float hi, sc;
    int use_n;
    if (!bad) {
        hi = (float)(thr_t[b] + 4) * (1.0f / 64.0f);
        sc = 1024.0f / hi;
        use_n = cn;
        for (int c = tid; c < cn; c += 256) {
            float d = cd[(size_t)b * CAP + c];
            ldist[c] = d;
            lidx[c] = (int)(cand[(size_t)b * CAP + c] & 0x1FFFFu);
            int bn = (int)(d * sc);
            bn = bn < 0 ? 0 : (bn > 1023 ? 1023 : bn);
            atomicAdd(&hist[bn], 1);
        }
    } else {
        // exact brute-force over all N_DB (correctness guarantee; ~never taken)
        hi = 4.0f; sc = 256.0f; use_n = -1;
        for (int n = tid; n < N_DB; n += 256) {
            const float4* dr = (const float4*)(db_X + (size_t)n * D_F);
            float dot = 0.f;
            #pragma unroll
            for (int k = 0; k < 16; k++) {
                float4 w = dr[k];
                dot += xrow[k * 4 + 0] * w.x + xrow[k * 4 + 1] * w.y
                     + xrow[k * 4 + 2] * w.z + xrow[k * 4 + 3] * w.w;
            }
            float d = (xx - 2.0f * dot + d2[n]) * (1.0f / D_F);
            int bn = (int)(d * sc);
            bn = bn < 0 ? 0 : (bn > 1023 ? 1023 : bn);
            atomicAdd(&hist[bn], 1);
        }
    }
    __syncthreads();

    // 100th-smallest bin: 4-wide partials then serial scan
    {
        int t4 = hist[4 * tid] + hist[4 * tid + 1] + hist[4 * tid + 2] + hist[4 * tid + 3];
        s4[tid] = t4;
    }
    __syncthreads();
    if (tid == 0) {
        int cum = 0, bsel = 1023, c0 = 0;
        for (int g = 0; g < 256; g++) {
            if (cum + s4[g] >= K_NN) {
                int c2 = cum;
                bsel = g * 4 + 3;
                for (int e = 0; e < 4; e++) {
                    if (c2 + hist[g * 4 + e] >= K_NN) { bsel = g * 4 + e; break; }
                    c2 += hist[g * 4 + e];
                }
                c0 = c2;
                break;
            }
            cum += s4[g];
        }
        s_b100 = bsel; s_c0 = c0;
    }
    __syncthreads();
    int b100 = s_b100, c0 = s_c0;      // c0 < 100 entries strictly below bin b100

    // emit definite members; collect boundary bin
    if (!bad) {
        for (int c = tid; c < use_n; c += 256) {
            float d = ldist[c];
            int bn = (int)(d * sc);
            bn = bn < 0 ? 0 : (bn > 1023 ? 1023 : bn);
            if (bn < b100) {
                int pos = atomicAdd(&s_out, 1);
                idx[(size_t)b * K_NN + pos] = lidx[c];
            } else if (bn == b100) {
                int pos = atomicAdd(&s_bb, 1);
                if (pos < BB) { bbd[pos] = d; bbn[pos] = lidx[c]; }
            }
        }
    } else {
        for (int n = tid; n < N_DB; n += 256) {
            const float4* dr = (const float4*)(db_X + (size_t)n * D_F);
            float dot = 0.f;
            #pragma unroll
            for (int k = 0; k < 16; k++) {
                float4 w = dr[k];
                dot += xrow[k * 4 + 0] * w.x + xrow[k * 4 + 1] * w.y
                     + xrow[k * 4 + 2] * w.z + xrow[k * 4 + 3] * w.w;
            }
            float d = (xx - 2.0f * dot + d2[n]) * (1.0f / D_F);
            int bn = (int)(d * sc);
            bn = bn < 0 ? 0 : (bn > 1023 ? 1023 : bn);
            if (bn < b100) {
                int pos = atomicAdd(&s_out, 1);
                idx[(size_t)b * K_NN + pos] = n;
            } else if (bn == b100) {
                int pos = atomicAdd(&s_bb, 1);
                if (pos < BB) { bbd[pos] = d; bbn[pos] = n; }
            }
        }
    }
    __syncthreads();

    // boundary mini-rank: take (K - c0) smallest by (dist, idx)
    int m = K_NN - c0;
    int bc = s_bb; if (bc > BB) bc = BB;
    for (int c = tid; c < bc; c += 256) {
        float dc = bbd[c]; int nc = bbn[c];
        int rank = 0;
        for (int j = 0; j < bc; j++) {
            float dj = bbd[j];
            rank += (dj < dc) || (dj == dc && bbn[j] < nc);
        }
        if (rank < m) {
            int pos = atomicAdd(&s_out, 1);
            idx[(size_t)b * K_NN + pos] = nc;
        }
    }
}

// ---------------- per-row regression + loss (augmented RHS, wave back-sub) ----------------
__global__ __launch_bounds__(256) void k_regress(
    const float* __restrict__ input, const float* __restrict__ target,
    const float* __restrict__ db_X, const float* __restrict__ db_y,
    const int* __restrict__ idx, float* __restrict__ out) {
    int b = blockIdx.x, tid = threadIdx.x;
    __shared__ float A[K_NN * AST];
    __shared__ float M[65 * AST];
    __shared__ float v[65], xa[68], yv[K_NN];
    __shared__ int nbr[K_NN];

    if (tid < K_NN) {
        int n = idx[(size_t)b * K_NN + tid];
        nbr[tid] = n;
        yv[tid] = db_y[n];
    }
    if (tid < 64) xa[1 + tid] = input[(size_t)b * D_F + tid];
    if (tid == 0) { xa[0] = 1.f; xa[65] = xa[66] = xa[67] = 0.f; }
    __syncthreads();

    for (int f = tid; f < K_NN * AST; f += 256) {
        int k = f / AST, c = f - k * AST;
        float val = 0.f;
        if (c == 0) val = 1.f;
        else if (c <= 64) val = db_X[(size_t)nbr[k] * D_F + (c - 1)];
        A[f] = val;
    }
    __syncthreads();

    for (int tsk = tid; tsk < 289; tsk += 256) {
        int ti = tsk / 17, tj = tsk % 17;
        int p0 = ti * 4, q0 = tj * 4;
        float acc[4][4];
        #pragma unroll
        for (int ii = 0; ii < 4; ii++)
            #pragma unroll
            for (int jj = 0; jj < 4; jj++) acc[ii][jj] = 0.f;
        for (int k = 0; k < K_NN; k++) {
            float4 ap = *(const float4*)(&A[k * AST + p0]);
            float4 aq = *(const float4*)(&A[k * AST + q0]);
            float app[4] = {ap.x, ap.y, ap.z, ap.w};
            float aqq[4] = {aq.x, aq.y, aq.z, aq.w};
            #pragma unroll
            for (int ii = 0; ii < 4; ii++)
                #pragma unroll
                for (int jj = 0; jj < 4; jj++) acc[ii][jj] += app[ii] * aqq[jj];
        }
        #pragma unroll
        for (int ii = 0; ii < 4; ii++)
            #pragma unroll
            for (int jj = 0; jj < 4; jj++) {
                int p = p0 + ii, q = q0 + jj;
                if (p < 65 && q < 65)
                    M[p * AST + q] = acc[ii][jj] + (p == q ? JITTER : 0.f);
            }
    }
    for (int p = tid; p < 65; p += 256) {
        float s = 0.f;
        for (int k = 0; k < K_NN; k++) s += A[k * AST + p] * yv[k];
        M[p * AST + 65] = s;
    }
    __syncthreads();

    for (int j = 0; j < 65; j++) {
        float inv = 1.0f / M[j * AST + j];
        for (int c = j + 1 + (tid & 63); c <= 65; c += 64) {
            float mjc = M[j * AST + c] * inv;
            for (int i = j + 1 + (tid >> 6); i <= 64; i += 4)
                M[i * AST + c] -= M[i * AST + j] * mjc;
        }
        __syncthreads();
    }

    if (tid < 64) {
        int i = tid;
        float ri = M[i * AST + 65];
        float di = M[i * AST + i];
        float x64 = M[64 * AST + 65] / M[64 * AST + 64];
        ri -= M[i * AST + 64] * x64;
        float xi_out = 0.f;
        for (int j = 63; j >= 0; j--) {
            float xj = __shfl(ri, j, 64) / __shfl(di, j, 64);
            if (i == j) xi_out = xj;
            if (i < j) ri -= M[i * AST + j] * xj;
        }
        v[i] = xi_out;
        if (i == 0) v[64] = x64;
    }
    __syncthreads();

    if (tid == 0) {
        float pred = 0.f;
        for (int q = 0; q <= 64; q++) pred += xa[q] * v[q];
        float e = pred - target[b];
        atomicAdd(out, e * e * (1.0f / B_Q));
    }
}

extern "C" void kernel_launch(void* const* d_in, const int* in_sizes, int n_in,
                              void* d_out, int out_size, void* d_ws, size_t ws_size,
                              hipStream_t stream) {
    const float* input  = (const float*)d_in[0];
    const float* target = (const float*)d_in[1];
    const float* db_X   = (const float*)d_in[2];
    const float* db_y   = (const float*)d_in[3];
    float* out = (float*)d_out;

    char* ws = (char*)d_ws;
    size_t off = 0;
    auto alloc = [&](size_t bytes) {
        size_t o = off;
        off += (bytes + 255) & ~(size_t)255;
        return o;
    };
    float*    d2    = (float*)(ws + alloc((size_t)N_DB * 4));
    float*    x2    = (float*)(ws + alloc((size_t)B_Q * 4));
    int*      idx   = (int*)(ws + alloc((size_t)B_Q * K_NN * 4));
    int*      thr_t = (int*)(ws + alloc((size_t)B_Q * 4));
    int*      cnt   = (int*)(ws + alloc((size_t)B_Q * 4));
    int*      nle   = (int*)(ws + alloc((size_t)B_Q * 4));
    unsigned* cand  = (unsigned*)(ws + alloc((size_t)B_Q * CAP * 4));
    float*    cd    = (float*)(ws + alloc((size_t)B_Q * CAP * 4));
    unsigned short* dbb = (unsigned short*)(ws + alloc((size_t)N_DB * 64 * 2));
    unsigned short* inb = (unsigned short*)(ws + alloc((size_t)B_Q * 64 * 2));
    unsigned char*  sbin = (unsigned char*)(ws + alloc((size_t)B_Q * NS));

    hipMemsetAsync(d_out, 0, sizeof(float) * out_size, stream);
    hipMemsetAsync(cnt, 0, (size_t)B_Q * 4, stream);
    hipMemsetAsync(nle, 0, (size_t)B_Q * 4, stream);

    k_prep<<<2048, 256, 0, stream>>>(db_X, input, dbb, inb);
    {
        int waves = N_DB + B_Q;
        k_sqnorm<<<(waves + 3) / 4, 256, 0, stream>>>(db_X, input, d2, x2);
    }
    k_gemm_sample<<<NS / 128, 256, 0, stream>>>(inb, dbb, x2, d2, sbin);
    k_thr<<<B_Q, 256, 0, stream>>>(sbin, thr_t);
    k_gemm_cand<<<(N_DB + 127) / 128, 256, 0, stream>>>(inb, dbb, x2, d2, thr_t, cnt, nle, cand);
    k_refine<<<B_Q, 256, 0, stream>>>(cnt, cand, input, db_X, x2, d2, cd);
    k_rank<<<B_Q, 256, 0, stream>>>(cnt, nle, cand, cd, thr_t, input, db_X, x2, d2, idx);
    k_regress<<<B_Q, 256, 0, stream>>>(input, target, db_X, db_y, idx, out);
}

// Round 9
// 355.520 us; speedup vs baseline: 3.5787x; 1.6483x over previous
//
#include <hip/hip_runtime.h>

#define N_DB   100000
#define B_Q    1024
#define D_F    64
#define K_NN   100
#define JITTER 1e-6f
#define NS     12544   // prefix-sample cols = 98*128
#define STGT   40      // sample cum target (1/8 sample -> full count >= 100 w.h.p.)
#define NT     782     // n-tiles = ceil(N_DB/128)
#define SLOT   16      // per-(tile,row) candidate slots
#define CAP    3072    // per-row dense candidate capacity
#define BB     512     // boundary-bin capacity in k_rank
#define TP     80      // padded LDS k-stride (bf16 elems)
#define AST    68      // k_regress LDS row stride (f32)

typedef __attribute__((ext_vector_type(8))) short bf16x8;
typedef __attribute__((ext_vector_type(4))) float f32x4;

__device__ __forceinline__ unsigned short f2b(float x) {   // f32 -> bf16 RNE
    unsigned u = __float_as_uint(x);
    u += 0x7FFF + ((u >> 16) & 1);
    return (unsigned short)(u >> 16);
}

// ---------------- fused bf16 copy + squared norms (16 lanes/row) ----------------
__global__ __launch_bounds__(256) void k_prep(
    const float* __restrict__ db_X, const float* __restrict__ input,
    unsigned short* __restrict__ dbb, unsigned short* __restrict__ inb,
    float* __restrict__ d2, float* __restrict__ x2) {
    int tid = threadIdx.x;
    int lane = tid & 63;
    int sub = lane & 15, grp = lane >> 4;
    int row = blockIdx.x * 16 + (tid >> 6) * 4 + grp;
    const int R = N_DB + B_Q;
    if (row >= R) return;
    const float* src = (row < N_DB) ? db_X + (size_t)row * 64 + sub * 4
                                    : input + (size_t)(row - N_DB) * 64 + sub * 4;
    unsigned short* dst = (row < N_DB) ? dbb + (size_t)row * 64 + sub * 4
                                       : inb + (size_t)(row - N_DB) * 64 + sub * 4;
    float4 w = *(const float4*)src;
    ushort4 o = { f2b(w.x), f2b(w.y), f2b(w.z), f2b(w.w) };
    *(ushort4*)dst = o;
    float s = w.x * w.x + w.y * w.y + w.z * w.z + w.w * w.w;
    s += __shfl_xor(s, 1, 64);
    s += __shfl_xor(s, 2, 64);
    s += __shfl_xor(s, 4, 64);
    s += __shfl_xor(s, 8, 64);
    if (sub == 0) {
        if (row < N_DB) d2[row] = s;
        else            x2[row - N_DB] = s;
    }
}

// ---------------- bf16 tile staging (from preconverted arrays) ----------------
__device__ __forceinline__ void stage_rows_bf16(
    const unsigned short* __restrict__ src, unsigned short* dst,
    int n0, int tid, bool guard) {
    #pragma unroll
    for (int it = 0; it < 4; it++) {               // 1024 short8 = 128 rows x 8 chunks
        int f = it * 256 + tid;
        int c = f >> 3, k8 = f & 7;
        int n = n0 + c;
        uint4 w = make_uint4(0u, 0u, 0u, 0u);
        if (!guard || n < N_DB) w = *(const uint4*)(src + (size_t)n * 64 + k8 * 8);
        *(uint4*)(&dst[c * TP + k8 * 8]) = w;
    }
}

__device__ __forceinline__ void mfma_tile(
    const unsigned short* As, const unsigned short* Bs,
    int wr, int wc, int fr, int fq, f32x4 acc[4][4]) {
    #pragma unroll
    for (int ks = 0; ks < 2; ks++) {
        int koff = fq * 8 + ks * 32;
        bf16x8 a[4], b[4];
        #pragma unroll
        for (int i = 0; i < 4; i++)
            a[i] = *(const bf16x8*)(&As[(wr + i * 16 + fr) * TP + koff]);
        #pragma unroll
        for (int j = 0; j < 4; j++)
            b[j] = *(const bf16x8*)(&Bs[(wc + j * 16 + fr) * TP + koff]);
        #pragma unroll
        for (int i = 0; i < 4; i++)
            #pragma unroll
            for (int j = 0; j < 4; j++)
                acc[i][j] = __builtin_amdgcn_mfma_f32_16x16x32_bf16(a[i], b[j], acc[i][j], 0, 0, 0);
    }
}

// ---------------- sample GEMM -> byte bins (2D grid, coalesced u32 stores) ----------------
__global__ __launch_bounds__(256) void k_gemm_sample(
    const unsigned short* __restrict__ inb, const unsigned short* __restrict__ dbb,
    const float* __restrict__ x2, const float* __restrict__ d2,
    unsigned char* __restrict__ sbin) {
    __shared__ unsigned short As[128 * TP];
    __shared__ unsigned short Bs[128 * TP];
    __shared__ float x2s[128], d2s[128];
    int tid = threadIdx.x;
    int n0 = blockIdx.x * 128;                     // < NS
    int b0 = blockIdx.y * 128;

    stage_rows_bf16(dbb, Bs, n0, tid, false);
    stage_rows_bf16(inb, As, b0, tid, false);
    if (tid < 128) {
        d2s[tid] = d2[n0 + tid];
        x2s[tid] = x2[b0 + tid];
    }
    __syncthreads();

    int lane = tid & 63, wid = tid >> 6;
    int wr = (wid >> 1) * 64, wc = (wid & 1) * 64;
    int fr = lane & 15, fq = lane >> 4;
    f32x4 acc[4][4];
    #pragma unroll
    for (int i = 0; i < 4; i++)
        #pragma unroll
        for (int j = 0; j < 4; j++) acc[i][j] = (f32x4){0.f, 0.f, 0.f, 0.f};
    mfma_tile(As, Bs, wr, wc, fr, fq, acc);

    const float inv_d = 1.0f / D_F;
    int jsel = fr >> 2;
    int base_src = (fq << 4) | (4 * (fr & 3));
    #pragma unroll
    for (int i = 0; i < 4; i++) {
        #pragma unroll
        for (int r = 0; r < 4; r++) {
            int row = wr + i * 16 + fq * 4 + r;    // C/D: col=lane&15, row=(lane>>4)*4+reg
            float xx = x2s[row];
            unsigned p = 0;
            #pragma unroll
            for (int j = 0; j < 4; j++) {
                int col = wc + j * 16 + fr;
                float dv = (xx + d2s[col] - 2.0f * acc[i][j][r]) * inv_d;
                int bin = (int)(dv * 64.0f);
                bin = bin < 0 ? 0 : (bin > 255 ? 255 : bin);
                p |= (unsigned)bin << (8 * j);
            }
            unsigned out = 0;
            #pragma unroll
            for (int e = 0; e < 4; e++) {
                unsigned q = __shfl(p, base_src + e, 64);
                out |= ((q >> (8 * jsel)) & 255u) << (8 * e);
            }
            int ncol = n0 + wc + 4 * fr;
            *(unsigned*)(sbin + (size_t)(b0 + row) * NS + ncol) = out;
        }
    }
}

// ---------------- per-row sample histogram -> threshold bin ----------------
__global__ __launch_bounds__(256) void k_thr(
    const unsigned char* __restrict__ sbin, int* __restrict__ thr_t) {
    int b = blockIdx.x, tid = threadIdx.x;
    __shared__ int hist[256];
    hist[tid] = 0;
    __syncthreads();
    const uint4* row4 = (const uint4*)(sbin + (size_t)b * NS);
    for (int v = tid; v < NS / 16; v += 256) {
        uint4 w = row4[v];
        unsigned ws[4] = {w.x, w.y, w.z, w.w};
        #pragma unroll
        for (int q = 0; q < 4; q++)
            #pragma unroll
            for (int e = 0; e < 4; e++)
                atomicAdd(&hist[(ws[q] >> (8 * e)) & 255u], 1);
    }
    __syncthreads();
    if (tid == 0) {
        int cum = 0, t = 255;
        for (int i = 0; i < 256; i++) {
            cum += hist[i];
            if (cum >= STGT) { t = i; break; }
        }
        thr_t[b] = t;
    }
}

// ---------------- full GEMM -> per-(tile,row) slots, ZERO global atomics ----------------
// loose emit: 64*dv < t+3  <=>  acc > (xx-(t+3))/2 + d2/2
// tight cnt:  64*dv < t+1  <=>  acc > (xx-(t+1))/2 + d2/2
__global__ __launch_bounds__(256) void k_gemm_cand(
    const unsigned short* __restrict__ inb, const unsigned short* __restrict__ dbb,
    const float* __restrict__ x2, const float* __restrict__ d2,
    const int* __restrict__ thr_t, unsigned char* __restrict__ counts,
    unsigned char* __restrict__ nle2, unsigned* __restrict__ cand2) {
    __shared__ unsigned short As[128 * TP];
    __shared__ unsigned short Bs[128 * TP];
    __shared__ float d2h[128], rl[128], rt[128];
    __shared__ int rowcnt[128], rtc[128];
    __shared__ unsigned slots[128 * SLOT];
    int tid = threadIdx.x;
    int n0 = blockIdx.x * 128;
    int b0 = blockIdx.y * 128;

    stage_rows_bf16(dbb, Bs, n0, tid, true);
    stage_rows_bf16(inb, As, b0, tid, false);
    if (tid < 128) {
        int n = n0 + tid;
        d2h[tid] = (n < N_DB) ? d2[n] * 0.5f : 1e30f;  // pad cols can never hit
        float xx = x2[b0 + tid];
        int t = thr_t[b0 + tid];
        rl[tid] = (xx - (float)(t + 3)) * 0.5f;
        rt[tid] = (xx - (float)(t + 1)) * 0.5f;
        rowcnt[tid] = 0; rtc[tid] = 0;
    }
    __syncthreads();

    int lane = tid & 63, wid = tid >> 6;
    int wr = (wid >> 1) * 64, wc = (wid & 1) * 64;
    int fr = lane & 15, fq = lane >> 4;
    f32x4 acc[4][4];
    #pragma unroll
    for (int i = 0; i < 4; i++)
        #pragma unroll
        for (int j = 0; j < 4; j++) acc[i][j] = (f32x4){0.f, 0.f, 0.f, 0.f};
    mfma_tile(As, Bs, wr, wc, fr, fq, acc);

    #pragma unroll
    for (int i = 0; i < 4; i++) {
        #pragma unroll
        for (int r = 0; r < 4; r++) {
            int row = wr + i * 16 + fq * 4 + r;
            float rlv = rl[row], rtv = rt[row];
            #pragma unroll
            for (int j = 0; j < 4; j++) {
                int col = wc + j * 16 + fr;
                float a = acc[i][j][r];
                float dh = d2h[col];
                if (a > rlv + dh) {                // loose hit (superset)
                    int pos = atomicAdd(&rowcnt[row], 1);      // LDS atomic only
                    if (pos < SLOT) slots[row * SLOT + pos] = (unsigned)(n0 + col);
                    if (a > rtv + dh) atomicAdd(&rtc[row], 1); // tight
                }
            }
        }
    }
    __syncthreads();

    // coalesced flush: counts/nle2 layout [tile][global_row]; cand2 [tile][global_row][SLOT]
    size_t gb = (size_t)blockIdx.x * B_Q + b0;
    if (tid < 128) {
        int rc = rowcnt[tid]; counts[gb + tid] = (unsigned char)(rc > 255 ? 255 : rc);
        int tc = rtc[tid];    nle2[gb + tid]   = (unsigned char)(tc > 255 ? 255 : tc);
    }
    for (int e = tid; e < 128 * SLOT; e += 256)
        cand2[gb * SLOT + e] = slots[e];           // 8KB contiguous per block
}

// ---------------- compact slots -> dense list + exact f32 distances ----------------
__global__ __launch_bounds__(256) void k_refine(
    const unsigned char* __restrict__ counts, const unsigned char* __restrict__ nle2,
    const unsigned* __restrict__ cand2, const float* __restrict__ input,
    const float* __restrict__ db_X, const float* __restrict__ x2,
    const float* __restrict__ d2, float* __restrict__ cdG, int* __restrict__ ciG,
    int* __restrict__ cntF, int* __restrict__ nleF, int* __restrict__ badF) {
    int b = blockIdx.x, tid = threadIdx.x, lane = tid & 63;
    __shared__ float xrow[64];
    __shared__ int lidx[CAP];
    __shared__ int s_cnt, s_nle, s_bad;
    if (tid < 64) xrow[tid] = input[(size_t)b * 64 + tid];
    if (tid == 0) { s_cnt = 0; s_nle = 0; s_bad = 0; }
    __syncthreads();

    int tight = 0, bad = 0;
    for (int t = tid; t < NT; t += 256) {
        int c = counts[(size_t)t * B_Q + b];
        tight += nle2[(size_t)t * B_Q + b];
        if (c > SLOT) { bad = 1; c = SLOT; }
        const unsigned* sp = cand2 + ((size_t)t * B_Q + b) * SLOT;
        for (int e = 0; e < c; e++) {
            int pos = atomicAdd(&s_cnt, 1);
            if (pos < CAP) lidx[pos] = (int)sp[e];
            else bad = 1;
        }
    }
    #pragma unroll
    for (int off = 32; off; off >>= 1) tight += __shfl_xor(tight, off, 64);
    if (lane == 0) atomicAdd(&s_nle, tight);
    if (bad) atomicOr(&s_bad, 1);
    __syncthreads();

    int cn = s_cnt > CAP ? CAP : s_cnt;
    float xx = x2[b];
    for (int c = tid; c < cn; c += 256) {
        int n = lidx[c];
        const float4* dr = (const float4*)(db_X + (size_t)n * D_F);
        float dot = 0.f;
        #pragma unroll
        for (int k = 0; k < 16; k++) {
            float4 w = dr[k];
            dot += xrow[k * 4 + 0] * w.x + xrow[k * 4 + 1] * w.y
                 + xrow[k * 4 + 2] * w.z + xrow[k * 4 + 3] * w.w;
        }
        cdG[(size_t)b * CAP + c] = (xx - 2.0f * dot + d2[n]) * (1.0f / D_F);
        ciG[(size_t)b * CAP + c] = n;
    }
    if (tid == 0) {
        cntF[b] = cn;
        nleF[b] = s_nle;
        badF[b] = s_bad;
    }
}

// ---------------- exact top-100 via fine histogram + boundary mini-rank ----------------
__global__ __launch_bounds__(256) void k_rank(
    const int* __restrict__ cntF, const int* __restrict__ nleF,
    const int* __restrict__ badF, const float* __restrict__ cdG,
    const int* __restrict__ ciG, const int* __restrict__ thr_t,
    const float* __restrict__ input, const float* __restrict__ db_X,
    const float* __restrict__ x2, const float* __restrict__ d2,
    int* __restrict__ idx) {
    int b = blockIdx.x, tid = threadIdx.x;
    __shared__ float ldist[CAP];
    __shared__ int lidx[CAP];
    __shared__ int hist[1024];
    __shared__ int s4[256];
    __shared__ float bbd[BB];
    __shared__ int bbn[BB];
    __shared__ int s_b100, s_c0, s_out, s_bb;
    __shared__ float xrow[64];

    if (tid < 64) xrow[tid] = input[(size_t)b * 64 + tid];
    #pragma unroll
    for (int h = 0; h < 4; h++) hist[h * 256 + tid] = 0;
    if (tid == 0) { s_out = 0; s_bb = 0; }
    __syncthreads();

    int cn = cntF[b];
    bool bad = (badF[b] != 0) || (nleF[b] < K_NN);
    float xx = x2[b];

    float sc;
    if (!bad) {
        float hi = (float)(thr_t[b] + 4) * (1.0f / 64.0f);
        sc = 1024.0f / hi;
        for (int c = tid; c < cn; c += 256) {
            float d = cdG[(size_t)b * CAP + c];
            ldist[c] = d;
            lidx[c] = ciG[(size_t)b * CAP + c];
            int bn = (int)(d * sc);
            bn = bn < 0 ? 0 : (bn > 1023 ? 1023 : bn);
            atomicAdd(&hist[bn], 1);
        }
    } else {
        // exact brute-force over all N_DB (correctness guarantee; ~never taken)
        sc = 256.0f;
        for (int n = tid; n < N_DB; n += 256) {
            const float4* dr = (const float4*)(db_X + (size_t)n * D_F);
            float dot = 0.f;
            #pragma unroll
            for (int k = 0; k < 16; k++) {
                float4 w = dr[k];
                dot += xrow[k * 4 + 0] * w.x + xrow[k * 4 + 1] * w.y
                     + xrow[k * 4 + 2] * w.z + xrow[k * 4 + 3] * w.w;
            }
            float d = (xx - 2.0f * dot + d2[n]) * (1.0f / D_F);
            int bn = (int)(d * sc);
            bn = bn < 0 ? 0 : (bn > 1023 ? 1023 : bn);
            atomicAdd(&hist[bn], 1);
        }
    }
    __syncthreads();

    {
        int t4 = hist[4 * tid] + hist[4 * tid + 1] + hist[4 * tid + 2] + hist[4 * tid + 3];
        s4[tid] = t4;
    }
    __syncthreads();
    if (tid == 0) {
        int cum = 0, bsel = 1023, c0 = 0;
        for (int g = 0; g < 256; g++) {
            if (cum + s4[g] >= K_NN) {
                int c2 = cum;
                bsel = g * 4 + 3;
                for (int e = 0; e < 4; e++) {
                    if (c2 + hist[g * 4 + e] >= K_NN) { bsel = g * 4 + e; break; }
                    c2 += hist[g * 4 + e];
                }
                c0 = c2;
                break;
            }
            cum += s4[g];
        }
        s_b100 = bsel; s_c0 = c0;
    }
    __syncthreads();
    int b100 = s_b100, c0 = s_c0;      // c0 < 100 entries strictly below bin b100

    if (!bad) {
        for (int c = tid; c < cn; c += 256) {
            float d = ldist[c];
            int bn = (int)(d * sc);
            bn = bn < 0 ? 0 : (bn > 1023 ? 1023 : bn);
            if (bn < b100) {
                int pos = atomicAdd(&s_out, 1);
                idx[(size_t)b * K_NN + pos] = lidx[c];
            } else if (bn == b100) {
                int pos = atomicAdd(&s_bb, 1);
                if (pos < BB) { bbd[pos] = d; bbn[pos] = lidx[c]; }
            }
        }
    } else {
        for (int n = tid; n < N_DB; n += 256) {
            const float4* dr = (const float4*)(db_X + (size_t)n * D_F);
            float dot = 0.f;
            #pragma unroll
            for (int k = 0; k < 16; k++) {
                float4 w = dr[k];
                dot += xrow[k * 4 + 0] * w.x + xrow[k * 4 + 1] * w.y
                     + xrow[k * 4 + 2] * w.z + xrow[k * 4 + 3] * w.w;
            }
            float d = (xx - 2.0f * dot + d2[n]) * (1.0f / D_F);
            int bn = (int)(d * sc);
            bn = bn < 0 ? 0 : (bn > 1023 ? 1023 : bn);
            if (bn < b100) {
                int pos = atomicAdd(&s_out, 1);
                idx[(size_t)b * K_NN + pos] = n;
            } else if (bn == b100) {
                int pos = atomicAdd(&s_bb, 1);
                if (pos < BB) { bbd[pos] = d; bbn[pos] = n; }
            }
        }
    }
    __syncthreads();

    int m = K_NN - c0;
    int bc = s_bb; if (bc > BB) bc = BB;
    for (int c = tid; c < bc; c += 256) {
        float dc = bbd[c]; int nc = bbn[c];
        int rank = 0;
        for (int j = 0; j < bc; j++) {
            float dj = bbd[j];
            rank += (dj < dc) || (dj == dc && bbn[j] < nc);
        }
        if (rank < m) {
            int pos = atomicAdd(&s_out, 1);
            idx[(size_t)b * K_NN + pos] = nc;
        }
    }
}

// ---------------- per-row regression + loss (augmented RHS, wave back-sub) ----------------
__global__ __launch_bounds__(256) void k_regress(
    const float* __restrict__ input, const float* __restrict__ target,
    const float* __restrict__ db_X, const float* __restrict__ db_y,
    const int* __restrict__ idx, float* __restrict__ out) {
    int b = blockIdx.x, tid = threadIdx.x;
    __shared__ float A[K_NN * AST];
    __shared__ float M[65 * AST];
    __shared__ float v[65], xa[68], yv[K_NN];
    __shared__ int nbr[K_NN];

    if (tid < K_NN) {
        int n = idx[(size_t)b * K_NN + tid];
        nbr[tid] = n;
        yv[tid] = db_y[n];
    }
    if (tid < 64) xa[1 + tid] = input[(size_t)b * D_F + tid];
    if (tid == 0) { xa[0] = 1.f; xa[65] = xa[66] = xa[67] = 0.f; }
    __syncthreads();

    for (int f = tid; f < K_NN * AST; f += 256) {
        int k = f / AST, c = f - k * AST;
        float val = 0.f;
        if (c == 0) val = 1.f;
        else if (c <= 64) val = db_X[(size_t)nbr[k] * D_F + (c - 1)];
        A[f] = val;
    }
    __syncthreads();

    for (int tsk = tid; tsk < 289; tsk += 256) {
        int ti = tsk / 17, tj = tsk % 17;
        int p0 = ti * 4, q0 = tj * 4;
        float acc[4][4];
        #pragma unroll
        for (int ii = 0; ii < 4; ii++)
            #pragma unroll
            for (int jj = 0; jj < 4; jj++) acc[ii][jj] = 0.f;
        for (int k = 0; k < K_NN; k++) {
            float4 ap = *(const float4*)(&A[k * AST + p0]);
            float4 aq = *(const float4*)(&A[k * AST + q0]);
            float app[4] = {ap.x, ap.y, ap.z, ap.w};
            float aqq[4] = {aq.x, aq.y, aq.z, aq.w};
            #pragma unroll
            for (int ii = 0; ii < 4; ii++)
                #pragma unroll
                for (int jj = 0; jj < 4; jj++) acc[ii][jj] += app[ii] * aqq[jj];
        }
        #pragma unroll
        for (int ii = 0; ii < 4; ii++)
            #pragma unroll
            for (int jj = 0; jj < 4; jj++) {
                int p = p0 + ii, q = q0 + jj;
                if (p < 65 && q < 65)
                    M[p * AST + q] = acc[ii][jj] + (p == q ? JITTER : 0.f);
            }
    }
    for (int p = tid; p < 65; p += 256) {
        float s = 0.f;
        for (int k = 0; k < K_NN; k++) s += A[k * AST + p] * yv[k];
        M[p * AST + 65] = s;
    }
    __syncthreads();

    for (int j = 0; j < 65; j++) {
        float inv = 1.0f / M[j * AST + j];
        for (int c = j + 1 + (tid & 63); c <= 65; c += 64) {
            float mjc = M[j * AST + c] * inv;
            for (int i = j + 1 + (tid >> 6); i <= 64; i += 4)
                M[i * AST + c] -= M[i * AST + j] * mjc;
        }
        __syncthreads();
    }

    if (tid < 64) {
        int i = tid;
        float ri = M[i * AST + 65];
        float di = M[i * AST + i];
        float x64 = M[64 * AST + 65] / M[64 * AST + 64];
        ri -= M[i * AST + 64] * x64;
        float xi_out = 0.f;
        for (int j = 63; j >= 0; j--) {
            float xj = __shfl(ri, j, 64) / __shfl(di, j, 64);
            if (i == j) xi_out = xj;
            if (i < j) ri -= M[i * AST + j] * xj;
        }
        v[i] = xi_out;
        if (i == 0) v[64] = x64;
    }
    __syncthreads();

    if (tid == 0) {
        float pred = 0.f;
        for (int q = 0; q <= 64; q++) pred += xa[q] * v[q];
        float e = pred - target[b];
        atomicAdd(out, e * e * (1.0f / B_Q));
    }
}

extern "C" void kernel_launch(void* const* d_in, const int* in_sizes, int n_in,
                              void* d_out, int out_size, void* d_ws, size_t ws_size,
                              hipStream_t stream) {
    const float* input  = (const float*)d_in[0];
    const float* target = (const float*)d_in[1];
    const float* db_X   = (const float*)d_in[2];
    const float* db_y   = (const float*)d_in[3];
    float* out = (float*)d_out;

    char* ws = (char*)d_ws;
    size_t off = 0;
    auto alloc = [&](size_t bytes) {
        size_t o = off;
        off += (bytes + 255) & ~(size_t)255;
        return o;
    };
    float*    d2    = (float*)(ws + alloc((size_t)N_DB * 4));
    float*    x2    = (float*)(ws + alloc((size_t)B_Q * 4));
    int*      idx   = (int*)(ws + alloc((size_t)B_Q * K_NN * 4));
    int*      thr_t = (int*)(ws + alloc((size_t)B_Q * 4));
    int*      cntF  = (int*)(ws + alloc((size_t)B_Q * 4));
    int*      nleF  = (int*)(ws + alloc((size_t)B_Q * 4));
    int*      badF  = (int*)(ws + alloc((size_t)B_Q * 4));
    unsigned char* counts = (unsigned char*)(ws + alloc((size_t)NT * B_Q));
    unsigned char* nle2   = (unsigned char*)(ws + alloc((size_t)NT * B_Q));
    unsigned* cand2 = (unsigned*)(ws + alloc((size_t)NT * B_Q * SLOT * 4));
    float*    cdG   = (float*)(ws + alloc((size_t)B_Q * CAP * 4));
    int*      ciG   = (int*)(ws + alloc((size_t)B_Q * CAP * 4));
    unsigned short* dbb = (unsigned short*)(ws + alloc((size_t)N_DB * 64 * 2));
    unsigned short* inb = (unsigned short*)(ws + alloc((size_t)B_Q * 64 * 2));
    unsigned char*  sbin = (unsigned char*)(ws + alloc((size_t)B_Q * NS));

    hipMemsetAsync(d_out, 0, sizeof(float) * out_size, stream);

    k_prep<<<(N_DB + B_Q + 15) / 16, 256, 0, stream>>>(db_X, input, dbb, inb, d2, x2);
    {
        dim3 g(NS / 128, B_Q / 128);
        k_gemm_sample<<<g, 256, 0, stream>>>(inb, dbb, x2, d2, sbin);
    }
    k_thr<<<B_Q, 256, 0, stream>>>(sbin, thr_t);
    {
        dim3 g(NT, B_Q / 128);
        k_gemm_cand<<<g, 256, 0, stream>>>(inb, dbb, x2, d2, thr_t, counts, nle2, cand2);
    }
    k_refine<<<B_Q, 256, 0, stream>>>(counts, nle2, cand2, input, db_X, x2, d2,
                                      cdG, ciG, cntF, nleF, badF);
    k_rank<<<B_Q, 256, 0, stream>>>(cntF, nleF, badF, cdG, ciG, thr_t,
                                    input, db_X, x2, d2, idx);
    k_regress<<<B_Q, 256, 0, stream>>>(input, target, db_X, db_y, idx, out);
}